// Round 7
// baseline (2348.568 us; speedup 1.0000x reference)
//
#include <hip/hip_runtime.h>
#include <hip/hip_cooperative_groups.h>

namespace cg = cooperative_groups;

#define HID 256
#define NFEAT 9
#define VOCAB 119
#define NLAYERS 4
#define NGRAPHS 256
#define BN_EPS 1e-5f

typedef short short8 __attribute__((ext_vector_type(8)));
typedef float floatx4 __attribute__((ext_vector_type(4)));

__device__ inline unsigned short f2bf(float f) {
    unsigned int u = __float_as_uint(f);
    unsigned int r = u + 0x7FFF + ((u >> 16) & 1);  // RNE
    return (unsigned short)(r >> 16);
}
__device__ inline float bf2f(unsigned short u) {
    return __uint_as_float(((unsigned int)u) << 16);
}

// ---------------- zero degi + fillc ----------------
__global__ void zero_kernel(int* __restrict__ degi, int* __restrict__ fillc, int N) {
    int i = blockIdx.x * blockDim.x + threadIdx.x;
    if (i < N) { degi[i] = 0; fillc[i] = 0; }
}

// ---------------- degree count (in-degree over dst) ----------------
__global__ void deg_kernel(const int* __restrict__ dst, int* __restrict__ degi, int E) {
    int i = blockIdx.x * blockDim.x + threadIdx.x;
    if (i < E) atomicAdd(&degi[dst[i]], 1);
}

// ---------------- parallel exclusive scan + nrm (single block, 1024 thr) ------
__global__ __launch_bounds__(1024) void scan_kernel(const int* __restrict__ degi,
                                                    int* __restrict__ row_ptr,
                                                    float* __restrict__ nrm, int N) {
    int tid = threadIdx.x;
    int ch = (N + 1023) >> 10;
    int i0 = tid * ch;
    int i1 = min(i0 + ch, N);
    if (i0 > N) i0 = N;
    int local = 0;
    for (int i = i0; i < i1; ++i) local += degi[i];
    int lane = tid & 63, wid = tid >> 6;
    int v = local;
#pragma unroll
    for (int off = 1; off < 64; off <<= 1) {
        int u = __shfl_up(v, off);
        if (lane >= off) v += u;
    }
    __shared__ int wsum[16];
    if (lane == 63) wsum[wid] = v;
    __syncthreads();
    if (tid < 16) {
        int w = wsum[tid];
#pragma unroll
        for (int off = 1; off < 16; off <<= 1) {
            int u = __shfl_up(w, off);
            if (tid >= off) w += u;
        }
        wsum[tid] = w;
    }
    __syncthreads();
    int base = (wid > 0 ? wsum[wid - 1] : 0) + (v - local);
    int run = base;
    for (int i = i0; i < i1; ++i) {
        int d = degi[i];
        row_ptr[i] = run;
        run += d;
        nrm[i] = rsqrtf(1.0f + (float)d);
    }
    if (tid == 0) row_ptr[N] = wsum[15];
}

// ---------------- CSR fill: interleaved (src, weight) edge records -------------
__global__ void fill_kernel(const int* __restrict__ src, const int* __restrict__ dst,
                            const int* __restrict__ row_ptr, int* __restrict__ fill,
                            const float* __restrict__ nrm,
                            int2* __restrict__ edges, int E) {
    int i = blockIdx.x * blockDim.x + threadIdx.x;
    if (i < E) {
        int d = dst[i];
        int s = src[i];
        int pos = row_ptr[d] + atomicAdd(&fill[d], 1);
        int2 rec;
        rec.x = s;
        rec.y = __float_as_int(nrm[s] * nrm[d]);
        edges[pos] = rec;
    }
}

// ---------------- weight transpose + bf16 convert: Wt[l][n][k] ----------------
__global__ __launch_bounds__(256) void wcvt_kernel(const float* __restrict__ W,
                                                   unsigned short* __restrict__ Wt) {
    __shared__ float s[32][33];
    int l = blockIdx.z;
    int k0 = blockIdx.x * 32, n0 = blockIdx.y * 32;
    int c = threadIdx.x & 31, r8 = threadIdx.x >> 5;
    const float* Wl = W + (size_t)l * HID * HID;
    unsigned short* Wtl = Wt + (size_t)l * HID * HID;
#pragma unroll
    for (int p = 0; p < 4; ++p) {
        int r = r8 + p * 8;
        s[r][c] = Wl[(k0 + r) * HID + n0 + c];
    }
    __syncthreads();
#pragma unroll
    for (int p = 0; p < 4; ++p) {
        int r = r8 + p * 8;
        Wtl[(size_t)(n0 + r) * HID + k0 + c] = f2bf(s[c][r]);
    }
}

// ---------------- persistent cooperative kernel: whole network ----------------
struct CoopParams {
    const int* x;
    const float* emb;
    const int* batch;
    const int* row_ptr;
    const int2* edges;
    const float* nrm;
    const unsigned short* wt;
    const float* b;
    const float* gamma;
    const float* beta;
    const float* W1; const float* b1;
    const float* W2; const float* b2;
    const float* W3; const float* b3;
    unsigned short* hbA;
    unsigned short* hbB;
    unsigned short* aggb;
    unsigned short* hwb;
    float* bnsums;
    float* out;
    int N;
};

__device__ __forceinline__ int lower_bound_g(const int* __restrict__ a, int n, int key) {
    int lo = 0, hi = n;
    while (lo < hi) {
        int mid = (lo + hi) >> 1;
        if (a[mid] < key) lo = mid + 1; else hi = mid;
    }
    return lo;
}

__global__ __launch_bounds__(256, 3) void coop_kernel(CoopParams p) {
    cg::grid_group grid = cg::this_grid();
    const int bx = blockIdx.x;
    const int GB = gridDim.x;
    const int tid = threadIdx.x;
    const int N = p.N;

    __shared__ unsigned short As[64][40];
    __shared__ unsigned short Bs[64][40];
    __shared__ float lsum[64];
    __shared__ float lsq[64];
    __shared__ int xf[NFEAT];
    __shared__ float gs[256];
    __shared__ float t1[128];
    __shared__ float t2[64];

    // ---- phase 0: zero bnsums (block 0) + atom-encoder embed -> hbA ----
    if (bx == 0) {
        for (int i = tid; i < NLAYERS * 2 * HID; i += 256) p.bnsums[i] = 0.f;
    }
    for (int n = bx; n < N; n += GB) {
        __syncthreads();
        if (tid < NFEAT) xf[tid] = p.x[n * NFEAT + tid];
        __syncthreads();
        float s = 0.f;
#pragma unroll
        for (int f = 0; f < NFEAT; ++f) s += p.emb[(size_t)(f * VOCAB + xf[f]) * HID + tid];
        p.hbA[(size_t)n * HID + tid] = f2bf(s);
    }
    __threadfence();
    grid.sync();

    unsigned short* hbcur = p.hbA;
    unsigned short* hboth = p.hbB;
    const int wave = tid >> 6;
    const int lane = tid & 63;

    for (int l = 0; l < NLAYERS; ++l) {
        // ---- agg phase: XCD half-sliced gather (R5-proven form) ----
        {
            int half = bx & 1;
            int c = half * 128 + lane * 2;
            const unsigned short* hbc = hbcur + c;
            int stride = (GB >> 1) * 4;
            for (int n = (bx >> 1) * 4 + wave; n < N; n += stride) {
                int s = p.row_ptr[n], e = p.row_ptr[n + 1];
                float ax = 0.f, ay = 0.f;
                int i = s;
                for (; i + 3 < e; i += 4) {
                    int2 e0 = p.edges[i], e1 = p.edges[i + 1];
                    int2 e2 = p.edges[i + 2], e3 = p.edges[i + 3];
                    ushort2 u0 = *(const ushort2*)&hbc[(size_t)e0.x * HID];
                    ushort2 u1 = *(const ushort2*)&hbc[(size_t)e1.x * HID];
                    ushort2 u2 = *(const ushort2*)&hbc[(size_t)e2.x * HID];
                    ushort2 u3 = *(const ushort2*)&hbc[(size_t)e3.x * HID];
                    float w0 = __int_as_float(e0.y), w1 = __int_as_float(e1.y);
                    float w2 = __int_as_float(e2.y), w3 = __int_as_float(e3.y);
                    ax += w0 * bf2f(u0.x) + w1 * bf2f(u1.x) + w2 * bf2f(u2.x) + w3 * bf2f(u3.x);
                    ay += w0 * bf2f(u0.y) + w1 * bf2f(u1.y) + w2 * bf2f(u2.y) + w3 * bf2f(u3.y);
                }
                for (; i < e; ++i) {
                    int2 e0 = p.edges[i];
                    ushort2 u0 = *(const ushort2*)&hbc[(size_t)e0.x * HID];
                    float w0 = __int_as_float(e0.y);
                    ax += w0 * bf2f(u0.x);
                    ay += w0 * bf2f(u0.y);
                }
                float nd = p.nrm[n];
                float sw = nd * nd;
                ushort2 us = *(const ushort2*)&hbc[(size_t)n * HID];
                ax += sw * bf2f(us.x);
                ay += sw * bf2f(us.y);
                ushort2 o;
                o.x = f2bf(ax);
                o.y = f2bf(ay);
                *(ushort2*)&p.aggb[(size_t)n * HID + c] = o;
            }
        }
        __threadfence();
        grid.sync();

        // ---- gemm phase: bf16 MFMA + bias + BN column stats ----
        {
            const unsigned short* Bt = p.wt + (size_t)l * HID * HID;
            const float* bias = p.b + (size_t)l * HID;
            float* sums = p.bnsums + (size_t)l * 2 * HID;
            int tiles = ((N + 63) >> 6) * 4;
            int lrow = tid >> 2;
            int lkc = (tid & 3) * 8;
            int wm = (wave & 1) * 32;
            int wn = (wave >> 1) * 32;
            int quad = lane >> 4;
            int ln = lane & 15;
            for (int t = bx; t < tiles; t += GB) {
                int row0 = (t >> 2) * 64;
                int col0 = (t & 3) * 64;
                if (tid < 64) { lsum[tid] = 0.f; lsq[tid] = 0.f; }
                floatx4 acc00 = {0.f, 0.f, 0.f, 0.f};
                floatx4 acc01 = {0.f, 0.f, 0.f, 0.f};
                floatx4 acc10 = {0.f, 0.f, 0.f, 0.f};
                floatx4 acc11 = {0.f, 0.f, 0.f, 0.f};
                for (int kk = 0; kk < HID; kk += 32) {
                    short8 av = {0, 0, 0, 0, 0, 0, 0, 0};
                    int ar = row0 + lrow;
                    if (ar < N) av = *(const short8*)&p.aggb[(size_t)ar * HID + kk + lkc];
                    short8 bv = *(const short8*)&Bt[(size_t)(col0 + lrow) * HID + kk + lkc];
                    *(short8*)&As[lrow][lkc] = av;
                    *(short8*)&Bs[lrow][lkc] = bv;
                    __syncthreads();
                    short8 a0 = *(const short8*)&As[wm + ln][quad * 8];
                    short8 a1 = *(const short8*)&As[wm + 16 + ln][quad * 8];
                    short8 b0 = *(const short8*)&Bs[wn + ln][quad * 8];
                    short8 b1 = *(const short8*)&Bs[wn + 16 + ln][quad * 8];
                    acc00 = __builtin_amdgcn_mfma_f32_16x16x32_bf16(a0, b0, acc00, 0, 0, 0);
                    acc01 = __builtin_amdgcn_mfma_f32_16x16x32_bf16(a0, b1, acc01, 0, 0, 0);
                    acc10 = __builtin_amdgcn_mfma_f32_16x16x32_bf16(a1, b0, acc10, 0, 0, 0);
                    acc11 = __builtin_amdgcn_mfma_f32_16x16x32_bf16(a1, b1, acc11, 0, 0, 0);
                    __syncthreads();
                }
                float bias0 = bias[col0 + wn + ln];
                float bias1 = bias[col0 + wn + 16 + ln];
                float p0 = 0.f, q0 = 0.f, p1 = 0.f, q1 = 0.f;
#pragma unroll
                for (int r = 0; r < 4; ++r) {
                    int row = row0 + wm + quad * 4 + r;
                    if (row < N) {
                        float v0 = acc00[r] + bias0;
                        float v1 = acc01[r] + bias1;
                        p.hwb[(size_t)row * HID + col0 + wn + ln] = f2bf(v0);
                        p.hwb[(size_t)row * HID + col0 + wn + 16 + ln] = f2bf(v1);
                        p0 += v0; q0 += v0 * v0;
                        p1 += v1; q1 += v1 * v1;
                    }
                    int row2 = row + 16;
                    if (row2 < N) {
                        float v0 = acc10[r] + bias0;
                        float v1 = acc11[r] + bias1;
                        p.hwb[(size_t)row2 * HID + col0 + wn + ln] = f2bf(v0);
                        p.hwb[(size_t)row2 * HID + col0 + wn + 16 + ln] = f2bf(v1);
                        p0 += v0; q0 += v0 * v0;
                        p1 += v1; q1 += v1 * v1;
                    }
                }
                atomicAdd(&lsum[wn + ln], p0);
                atomicAdd(&lsq[wn + ln], q0);
                atomicAdd(&lsum[wn + 16 + ln], p1);
                atomicAdd(&lsq[wn + 16 + ln], q1);
                __syncthreads();
                if (tid < 64) {
                    unsafeAtomicAdd(&sums[col0 + tid], lsum[tid]);
                    unsafeAtomicAdd(&sums[HID + col0 + tid], lsq[tid]);
                }
                __syncthreads();
            }
        }
        __threadfence();
        grid.sync();

        // ---- bn phase: BN + relu + residual, all bf16 ----
        {
            const float* sums = p.bnsums + (size_t)l * 2 * HID;
            const float* gam = p.gamma + (size_t)l * HID;
            const float* bet = p.beta + (size_t)l * HID;
            float invN = 1.0f / (float)N;
            int total = N * HID / 4;
            for (int i4 = bx * 256 + tid; i4 < total; i4 += GB * 256) {
                int base = i4 * 4;
                int c = base & (HID - 1);
                float4 s4 = *(const float4*)&sums[c];
                float4 q4 = *(const float4*)&sums[HID + c];
                float4 g4 = *(const float4*)&gam[c];
                float4 be4 = *(const float4*)&bet[c];
                ushort4 v = *(const ushort4*)&p.hwb[base];
                ushort4 r = *(const ushort4*)&hbcur[base];
                ushort4 o;
                float mu = s4.x * invN, var = q4.x * invN - mu * mu;
                o.x = f2bf(fmaxf((bf2f(v.x) - mu) * g4.x * rsqrtf(var + BN_EPS) + be4.x, 0.f) + bf2f(r.x));
                mu = s4.y * invN; var = q4.y * invN - mu * mu;
                o.y = f2bf(fmaxf((bf2f(v.y) - mu) * g4.y * rsqrtf(var + BN_EPS) + be4.y, 0.f) + bf2f(r.y));
                mu = s4.z * invN; var = q4.z * invN - mu * mu;
                o.z = f2bf(fmaxf((bf2f(v.z) - mu) * g4.z * rsqrtf(var + BN_EPS) + be4.z, 0.f) + bf2f(r.z));
                mu = s4.w * invN; var = q4.w * invN - mu * mu;
                o.w = f2bf(fmaxf((bf2f(v.w) - mu) * g4.w * rsqrtf(var + BN_EPS) + be4.w, 0.f) + bf2f(r.w));
                *(ushort4*)&hboth[base] = o;
            }
        }
        __threadfence();
        grid.sync();

        unsigned short* tb = hbcur; hbcur = hboth; hboth = tb;
    }

    // ---- pool + MLP phase: one block per graph ----
    if (bx < NGRAPHS) {
        int g = bx;
        int lo = lower_bound_g(p.batch, N, g);
        int hi = lower_bound_g(p.batch, N, g + 1);
        float s = 0.f;
        for (int i = lo; i < hi; ++i) s += bf2f(hbcur[(size_t)i * HID + tid]);
        float inv = 1.0f / fmaxf((float)(hi - lo), 1.0f);
        gs[tid] = s * inv;
        __syncthreads();
        if (tid < 128) {
            float a = p.b1[tid];
            for (int k = 0; k < 256; ++k) a += gs[k] * p.W1[k * 128 + tid];
            t1[tid] = fmaxf(a, 0.f);
        }
        __syncthreads();
        if (tid < 64) {
            float a = p.b2[tid];
            for (int k = 0; k < 128; ++k) a += t1[k] * p.W2[k * 64 + tid];
            t2[tid] = fmaxf(a, 0.f);
        }
        __syncthreads();
        if (tid < 64) {
            float pr = t2[tid] * p.W3[tid];
#pragma unroll
            for (int off = 32; off >= 1; off >>= 1) pr += __shfl_down(pr, off);
            if (tid == 0) p.out[g] = pr + p.b3[0];
        }
    }
}

extern "C" void kernel_launch(void* const* d_in, const int* in_sizes, int n_in,
                              void* d_out, int out_size, void* d_ws, size_t ws_size,
                              hipStream_t stream) {
    const int* x      = (const int*)d_in[0];
    const int* ei     = (const int*)d_in[1];
    const int* batch  = (const int*)d_in[2];
    const float* emb  = (const float*)d_in[3];
    const float* W    = (const float*)d_in[4];
    const float* b    = (const float*)d_in[5];
    const float* gamma= (const float*)d_in[6];
    const float* beta = (const float*)d_in[7];
    const float* W1   = (const float*)d_in[8];
    const float* b1   = (const float*)d_in[9];
    const float* W2   = (const float*)d_in[10];
    const float* b2   = (const float*)d_in[11];
    const float* W3   = (const float*)d_in[12];
    const float* b3   = (const float*)d_in[13];
    float* out = (float*)d_out;

    int N = in_sizes[0] / NFEAT;
    int E = in_sizes[1] / 2;
    const int* srcp = ei;
    const int* dstp = ei + E;

    char* ws = (char*)d_ws;
    auto alloc = [&](size_t bytes) -> char* {
        char* p = ws;
        ws += (bytes + 255) & ~(size_t)255;
        return p;
    };
    int* degi     = (int*)alloc((size_t)N * 4);
    int* row_ptr  = (int*)alloc((size_t)(N + 1) * 4);
    int* fillc    = (int*)alloc((size_t)N * 4);
    float* nrm    = (float*)alloc((size_t)N * 4);
    int2* edges   = (int2*)alloc((size_t)E * 8);
    unsigned short* hbA  = (unsigned short*)alloc((size_t)N * HID * 2);
    unsigned short* hbB  = (unsigned short*)alloc((size_t)N * HID * 2);
    unsigned short* aggb = (unsigned short*)alloc((size_t)N * HID * 2);
    unsigned short* hwb  = (unsigned short*)alloc((size_t)N * HID * 2);
    unsigned short* wt   = (unsigned short*)alloc((size_t)NLAYERS * HID * HID * 2);
    float* bnsums = (float*)alloc((size_t)NLAYERS * 2 * HID * 4);

    zero_kernel<<<(N + 255) / 256, 256, 0, stream>>>(degi, fillc, N);
    deg_kernel<<<(E + 255) / 256, 256, 0, stream>>>(dstp, degi, E);
    scan_kernel<<<1, 1024, 0, stream>>>(degi, row_ptr, nrm, N);
    fill_kernel<<<(E + 255) / 256, 256, 0, stream>>>(srcp, dstp, row_ptr, fillc, nrm, edges, E);
    wcvt_kernel<<<dim3(8, 8, NLAYERS), 256, 0, stream>>>(W, wt);

    CoopParams p;
    p.x = x; p.emb = emb; p.batch = batch;
    p.row_ptr = row_ptr; p.edges = edges; p.nrm = nrm;
    p.wt = wt; p.b = b; p.gamma = gamma; p.beta = beta;
    p.W1 = W1; p.b1 = b1; p.W2 = W2; p.b2 = b2; p.W3 = W3; p.b3 = b3;
    p.hbA = hbA; p.hbB = hbB; p.aggb = aggb; p.hwb = hwb;
    p.bnsums = bnsums; p.out = out;
    p.N = N;

    int nb = 0;
    hipOccupancyMaxActiveBlocksPerMultiprocessor(&nb, coop_kernel, 256, 0);
    if (nb < 1) nb = 1;
    int grid = nb * 256;          // 256 CUs on MI355X
    if (grid > 1024) grid = 1024;
    grid &= ~1;                   // even, for half-slicing
    if (grid < 2) grid = 2;

    void* args[] = {(void*)&p};
    hipLaunchCooperativeKernel(coop_kernel, dim3(grid), dim3(256), args, 0, stream);
}

// Round 8
// 347.183 us; speedup vs baseline: 6.7646x; 6.7646x over previous
//
#include <hip/hip_runtime.h>

#define HID 256
#define NFEAT 9
#define VOCAB 119
#define NLAYERS 4
#define NGRAPHS 256
#define BN_EPS 1e-5f

typedef short short8 __attribute__((ext_vector_type(8)));
typedef float floatx4 __attribute__((ext_vector_type(4)));

__device__ inline unsigned short f2bf(float f) {
    unsigned int u = __float_as_uint(f);
    unsigned int r = u + 0x7FFF + ((u >> 16) & 1);  // RNE
    return (unsigned short)(r >> 16);
}
__device__ inline float bf2f(unsigned short u) {
    return __uint_as_float(((unsigned int)u) << 16);
}

// ---------------- zero degi + fillc + bnsums ----------------
__global__ void zero_kernel(int* __restrict__ degi, int* __restrict__ fillc,
                            float* __restrict__ bnsums, int N) {
    int i = blockIdx.x * blockDim.x + threadIdx.x;
    if (i < N) { degi[i] = 0; fillc[i] = 0; }
    if (i < NLAYERS * 2 * HID) bnsums[i] = 0.f;
}

// ---------------- degree count (in-degree over dst) ----------------
__global__ void deg_kernel(const int* __restrict__ dst, int* __restrict__ degi, int E) {
    int i = blockIdx.x * blockDim.x + threadIdx.x;
    if (i < E) atomicAdd(&degi[dst[i]], 1);
}

// ---------------- parallel exclusive scan + nrm (single block, 1024 thr) ------
__global__ __launch_bounds__(1024) void scan_kernel(const int* __restrict__ degi,
                                                    int* __restrict__ row_ptr,
                                                    float* __restrict__ nrm, int N) {
    int tid = threadIdx.x;
    int ch = (N + 1023) >> 10;
    int i0 = tid * ch;
    int i1 = min(i0 + ch, N);
    if (i0 > N) i0 = N;
    int local = 0;
    for (int i = i0; i < i1; ++i) local += degi[i];
    int lane = tid & 63, wid = tid >> 6;
    int v = local;
#pragma unroll
    for (int off = 1; off < 64; off <<= 1) {
        int u = __shfl_up(v, off);
        if (lane >= off) v += u;
    }
    __shared__ int wsum[16];
    if (lane == 63) wsum[wid] = v;
    __syncthreads();
    if (tid < 16) {
        int w = wsum[tid];
#pragma unroll
        for (int off = 1; off < 16; off <<= 1) {
            int u = __shfl_up(w, off);
            if (tid >= off) w += u;
        }
        wsum[tid] = w;
    }
    __syncthreads();
    int base = (wid > 0 ? wsum[wid - 1] : 0) + (v - local);
    int run = base;
    for (int i = i0; i < i1; ++i) {
        int d = degi[i];
        row_ptr[i] = run;
        run += d;
        nrm[i] = rsqrtf(1.0f + (float)d);
    }
    if (tid == 0) row_ptr[N] = wsum[15];
}

// ---------------- CSR fill: interleaved (src, weight) edge records -------------
__global__ void fill_kernel(const int* __restrict__ src, const int* __restrict__ dst,
                            const int* __restrict__ row_ptr, int* __restrict__ fill,
                            const float* __restrict__ nrm,
                            int2* __restrict__ edges, int E) {
    int i = blockIdx.x * blockDim.x + threadIdx.x;
    if (i < E) {
        int d = dst[i];
        int s = src[i];
        int pos = row_ptr[d] + atomicAdd(&fill[d], 1);
        int2 rec;
        rec.x = s;
        rec.y = __float_as_int(nrm[s] * nrm[d]);
        edges[pos] = rec;
    }
}

// ---------------- weight transpose + bf16 convert: Wt[l][n][k] ----------------
__global__ __launch_bounds__(256) void wcvt_kernel(const float* __restrict__ W,
                                                   unsigned short* __restrict__ Wt) {
    __shared__ float s[32][33];
    int l = blockIdx.z;
    int k0 = blockIdx.x * 32, n0 = blockIdx.y * 32;
    int c = threadIdx.x & 31, r8 = threadIdx.x >> 5;
    const float* Wl = W + (size_t)l * HID * HID;
    unsigned short* Wtl = Wt + (size_t)l * HID * HID;
#pragma unroll
    for (int p = 0; p < 4; ++p) {
        int r = r8 + p * 8;
        s[r][c] = Wl[(k0 + r) * HID + n0 + c];
    }
    __syncthreads();
#pragma unroll
    for (int p = 0; p < 4; ++p) {
        int r = r8 + p * 8;
        Wtl[(size_t)(n0 + r) * HID + k0 + c] = f2bf(s[c][r]);
    }
}

// ---------------- atom encoder: sum of 9 per-feature embeddings ----------------
__global__ __launch_bounds__(256) void embed_kernel(const int* __restrict__ x,
                                                    const float* __restrict__ emb,
                                                    unsigned short* __restrict__ hb, int N) {
    int n = blockIdx.x;
    int c = threadIdx.x;
    __shared__ int xf[NFEAT];
    if (c < NFEAT) xf[c] = x[n * NFEAT + c];
    __syncthreads();
    float s = 0.f;
#pragma unroll
    for (int f = 0; f < NFEAT; ++f) s += emb[(size_t)(f * VOCAB + xf[f]) * HID + c];
    hb[(size_t)n * HID + c] = f2bf(s);
}

// ---------------- GCN aggregate: XCD half-slice, edge-parity sub-waves --------
// blockIdx%8 -> XCD; half = bx&1 constant per XCD -> 2.5 MB hb slice L2-resident.
// One wave per (node, half). Lanes 0-31 process even edges, 32-63 odd edges;
// each lane covers 4 cols (ushort4, 8B). Cross-sub-wave combine via shfl_xor(32).
// Halves VMEM/VALU issue per edge vs R5 with no wasted iterations.
__global__ __launch_bounds__(256) void agg_ep_kernel(const unsigned short* __restrict__ hb,
                                                     const int* __restrict__ row_ptr,
                                                     const int2* __restrict__ edges,
                                                     const float* __restrict__ nrm,
                                                     unsigned short* __restrict__ aggb, int N) {
    int bx = blockIdx.x;
    int half = bx & 1;
    int tid = threadIdx.x;
    int wave = tid >> 6;
    int lane = tid & 63;
    int sub = lane >> 5;
    int sl = lane & 31;
    int n = (bx >> 1) * 4 + wave;
    if (n >= N) return;
    int c = half * 128 + sl * 4;
    const unsigned short* hbc = hb + c;
    int s = row_ptr[n], e = row_ptr[n + 1];
    int len = e - s;
    float a0 = 0.f, a1 = 0.f, a2 = 0.f, a3 = 0.f;
    int it = sub;
    for (; it + 2 < len; it += 4) {   // this sub-wave: edges it and it+2 (2 gathers in flight)
        int2 e0 = edges[s + it];
        int2 e1 = edges[s + it + 2];
        ushort4 u0 = *(const ushort4*)&hbc[(size_t)e0.x * HID];
        ushort4 u1 = *(const ushort4*)&hbc[(size_t)e1.x * HID];
        float w0 = __int_as_float(e0.y);
        float w1 = __int_as_float(e1.y);
        a0 += w0 * bf2f(u0.x) + w1 * bf2f(u1.x);
        a1 += w0 * bf2f(u0.y) + w1 * bf2f(u1.y);
        a2 += w0 * bf2f(u0.z) + w1 * bf2f(u1.z);
        a3 += w0 * bf2f(u0.w) + w1 * bf2f(u1.w);
    }
    if (it < len) {
        int2 e0 = edges[s + it];
        ushort4 u0 = *(const ushort4*)&hbc[(size_t)e0.x * HID];
        float w0 = __int_as_float(e0.y);
        a0 += w0 * bf2f(u0.x);
        a1 += w0 * bf2f(u0.y);
        a2 += w0 * bf2f(u0.z);
        a3 += w0 * bf2f(u0.w);
    }
    // combine even/odd partial sums across sub-waves
    a0 += __shfl_xor(a0, 32);
    a1 += __shfl_xor(a1, 32);
    a2 += __shfl_xor(a2, 32);
    a3 += __shfl_xor(a3, 32);
    if (sub == 0) {
        float nd = nrm[n];
        float sw = nd * nd;
        ushort4 us = *(const ushort4*)&hbc[(size_t)n * HID];
        a0 += sw * bf2f(us.x);
        a1 += sw * bf2f(us.y);
        a2 += sw * bf2f(us.z);
        a3 += sw * bf2f(us.w);
        ushort4 o;
        o.x = f2bf(a0); o.y = f2bf(a1); o.z = f2bf(a2); o.w = f2bf(a3);
        *(ushort4*)&aggb[(size_t)n * HID + c] = o;
    }
}

// ---------------- bf16 MFMA GEMM + bias + fused BN column stats ----------------
__global__ __launch_bounds__(256) void mfma_gemm(const unsigned short* __restrict__ A,
                                                 const unsigned short* __restrict__ Bt,
                                                 const float* __restrict__ bias,
                                                 unsigned short* __restrict__ C,
                                                 float* __restrict__ sums, int M) {
    __shared__ unsigned short As[64][40];
    __shared__ unsigned short Bs[64][40];
    __shared__ float lsum[64];
    __shared__ float lsq[64];
    int tid = threadIdx.x;
    int row0 = blockIdx.x * 64;
    int col0 = blockIdx.y * 64;
    int lrow = tid >> 2;
    int lkc = (tid & 3) * 8;
    int lane = tid & 63;
    int wid = tid >> 6;
    int wm = (wid & 1) * 32;
    int wn = (wid >> 1) * 32;
    int quad = lane >> 4;
    int ln = lane & 15;

    floatx4 acc00 = {0.f, 0.f, 0.f, 0.f};
    floatx4 acc01 = {0.f, 0.f, 0.f, 0.f};
    floatx4 acc10 = {0.f, 0.f, 0.f, 0.f};
    floatx4 acc11 = {0.f, 0.f, 0.f, 0.f};

    if (tid < 64) { lsum[tid] = 0.f; lsq[tid] = 0.f; }

    for (int kk = 0; kk < HID; kk += 32) {
        short8 av = {0, 0, 0, 0, 0, 0, 0, 0};
        int ar = row0 + lrow;
        if (ar < M) av = *(const short8*)&A[(size_t)ar * HID + kk + lkc];
        short8 bv = *(const short8*)&Bt[(size_t)(col0 + lrow) * HID + kk + lkc];
        *(short8*)&As[lrow][lkc] = av;
        *(short8*)&Bs[lrow][lkc] = bv;
        __syncthreads();
        short8 a0 = *(const short8*)&As[wm + ln][quad * 8];
        short8 a1 = *(const short8*)&As[wm + 16 + ln][quad * 8];
        short8 b0 = *(const short8*)&Bs[wn + ln][quad * 8];
        short8 b1 = *(const short8*)&Bs[wn + 16 + ln][quad * 8];
        acc00 = __builtin_amdgcn_mfma_f32_16x16x32_bf16(a0, b0, acc00, 0, 0, 0);
        acc01 = __builtin_amdgcn_mfma_f32_16x16x32_bf16(a0, b1, acc01, 0, 0, 0);
        acc10 = __builtin_amdgcn_mfma_f32_16x16x32_bf16(a1, b0, acc10, 0, 0, 0);
        acc11 = __builtin_amdgcn_mfma_f32_16x16x32_bf16(a1, b1, acc11, 0, 0, 0);
        __syncthreads();
    }
    float bias0 = bias[col0 + wn + ln];
    float bias1 = bias[col0 + wn + 16 + ln];
    float p0 = 0.f, q0 = 0.f, p1 = 0.f, q1 = 0.f;
#pragma unroll
    for (int r = 0; r < 4; ++r) {
        int row = row0 + wm + quad * 4 + r;
        if (row < M) {
            float v0 = acc00[r] + bias0;
            float v1 = acc01[r] + bias1;
            C[(size_t)row * HID + col0 + wn + ln] = f2bf(v0);
            C[(size_t)row * HID + col0 + wn + 16 + ln] = f2bf(v1);
            p0 += v0; q0 += v0 * v0;
            p1 += v1; q1 += v1 * v1;
        }
        int row2 = row + 16;
        if (row2 < M) {
            float v0 = acc10[r] + bias0;
            float v1 = acc11[r] + bias1;
            C[(size_t)row2 * HID + col0 + wn + ln] = f2bf(v0);
            C[(size_t)row2 * HID + col0 + wn + 16 + ln] = f2bf(v1);
            p0 += v0; q0 += v0 * v0;
            p1 += v1; q1 += v1 * v1;
        }
    }
    atomicAdd(&lsum[wn + ln], p0);
    atomicAdd(&lsq[wn + ln], q0);
    atomicAdd(&lsum[wn + 16 + ln], p1);
    atomicAdd(&lsq[wn + 16 + ln], q1);
    __syncthreads();
    if (tid < 64) {
        unsafeAtomicAdd(&sums[col0 + tid], lsum[tid]);
        unsafeAtomicAdd(&sums[HID + col0 + tid], lsq[tid]);
    }
}

// ---------------- BN apply + relu + residual, all bf16 ------------------------
__global__ __launch_bounds__(256) void bn_kernel(const unsigned short* __restrict__ hwb,
                                                 const float* __restrict__ sums,
                                                 const float* __restrict__ gamma,
                                                 const float* __restrict__ beta,
                                                 const unsigned short* __restrict__ hold,
                                                 unsigned short* __restrict__ hbnew, int N) {
    int i4 = blockIdx.x * blockDim.x + threadIdx.x;
    int base = i4 * 4;
    if (base >= N * HID) return;
    int c = base & (HID - 1);
    float invN = 1.0f / (float)N;
    float4 s4 = *(const float4*)&sums[c];
    float4 q4 = *(const float4*)&sums[HID + c];
    float4 g4 = *(const float4*)&gamma[c];
    float4 be4 = *(const float4*)&beta[c];
    ushort4 v = *(const ushort4*)&hwb[base];
    ushort4 r = *(const ushort4*)&hold[base];
    ushort4 o;
    {
        float mu = s4.x * invN, var = q4.x * invN - mu * mu;
        o.x = f2bf(fmaxf((bf2f(v.x) - mu) * g4.x * rsqrtf(var + BN_EPS) + be4.x, 0.f) + bf2f(r.x));
        mu = s4.y * invN; var = q4.y * invN - mu * mu;
        o.y = f2bf(fmaxf((bf2f(v.y) - mu) * g4.y * rsqrtf(var + BN_EPS) + be4.y, 0.f) + bf2f(r.y));
        mu = s4.z * invN; var = q4.z * invN - mu * mu;
        o.z = f2bf(fmaxf((bf2f(v.z) - mu) * g4.z * rsqrtf(var + BN_EPS) + be4.z, 0.f) + bf2f(r.z));
        mu = s4.w * invN; var = q4.w * invN - mu * mu;
        o.w = f2bf(fmaxf((bf2f(v.w) - mu) * g4.w * rsqrtf(var + BN_EPS) + be4.w, 0.f) + bf2f(r.w));
    }
    *(ushort4*)&hbnew[base] = o;
}

// ---------------- fused mean-pool (binary search on sorted batch) + MLP -------
__device__ inline int lower_bound_g(const int* __restrict__ a, int n, int key) {
    int lo = 0, hi = n;
    while (lo < hi) {
        int mid = (lo + hi) >> 1;
        if (a[mid] < key) lo = mid + 1; else hi = mid;
    }
    return lo;
}

__global__ __launch_bounds__(256) void pool_mlp_kernel(const unsigned short* __restrict__ h,
                                                       const int* __restrict__ batch, int N,
                                                       const float* __restrict__ W1,
                                                       const float* __restrict__ b1,
                                                       const float* __restrict__ W2,
                                                       const float* __restrict__ b2,
                                                       const float* __restrict__ W3,
                                                       const float* __restrict__ b3,
                                                       float* __restrict__ out) {
    int g = blockIdx.x, tid = threadIdx.x;
    int lo = lower_bound_g(batch, N, g);
    int hi = lower_bound_g(batch, N, g + 1);
    float s = 0.f;
    for (int i = lo; i < hi; ++i) s += bf2f(h[(size_t)i * HID + tid]);
    __shared__ float gs[256];
    __shared__ float t1[128];
    __shared__ float t2[64];
    float inv = 1.0f / fmaxf((float)(hi - lo), 1.0f);
    gs[tid] = s * inv;
    __syncthreads();
    if (tid < 128) {
        float a = b1[tid];
        for (int k = 0; k < 256; ++k) a += gs[k] * W1[k * 128 + tid];
        t1[tid] = fmaxf(a, 0.f);
    }
    __syncthreads();
    if (tid < 64) {
        float a = b2[tid];
        for (int k = 0; k < 128; ++k) a += t1[k] * W2[k * 64 + tid];
        t2[tid] = fmaxf(a, 0.f);
    }
    __syncthreads();
    if (tid < 64) {
        float p = t2[tid] * W3[tid];
#pragma unroll
        for (int off = 32; off >= 1; off >>= 1) p += __shfl_down(p, off);
        if (tid == 0) out[g] = p + b3[0];
    }
}

extern "C" void kernel_launch(void* const* d_in, const int* in_sizes, int n_in,
                              void* d_out, int out_size, void* d_ws, size_t ws_size,
                              hipStream_t stream) {
    const int* x      = (const int*)d_in[0];
    const int* ei     = (const int*)d_in[1];
    const int* batch  = (const int*)d_in[2];
    const float* emb  = (const float*)d_in[3];
    const float* W    = (const float*)d_in[4];
    const float* b    = (const float*)d_in[5];
    const float* gamma= (const float*)d_in[6];
    const float* beta = (const float*)d_in[7];
    const float* W1   = (const float*)d_in[8];
    const float* b1   = (const float*)d_in[9];
    const float* W2   = (const float*)d_in[10];
    const float* b2   = (const float*)d_in[11];
    const float* W3   = (const float*)d_in[12];
    const float* b3   = (const float*)d_in[13];
    float* out = (float*)d_out;

    int N = in_sizes[0] / NFEAT;
    int E = in_sizes[1] / 2;
    const int* srcp = ei;
    const int* dstp = ei + E;

    char* ws = (char*)d_ws;
    auto alloc = [&](size_t bytes) -> char* {
        char* p = ws;
        ws += (bytes + 255) & ~(size_t)255;
        return p;
    };
    int* degi     = (int*)alloc((size_t)N * 4);
    int* row_ptr  = (int*)alloc((size_t)(N + 1) * 4);
    int* fillc    = (int*)alloc((size_t)N * 4);
    float* nrm    = (float*)alloc((size_t)N * 4);
    int2* edges   = (int2*)alloc((size_t)E * 8);
    unsigned short* hbA  = (unsigned short*)alloc((size_t)N * HID * 2);
    unsigned short* hbB  = (unsigned short*)alloc((size_t)N * HID * 2);
    unsigned short* aggb = (unsigned short*)alloc((size_t)N * HID * 2);
    unsigned short* hwb  = (unsigned short*)alloc((size_t)N * HID * 2);
    unsigned short* wt   = (unsigned short*)alloc((size_t)NLAYERS * HID * HID * 2);
    float* bnsums = (float*)alloc((size_t)NLAYERS * 2 * HID * 4);

    zero_kernel<<<(N + 255) / 256, 256, 0, stream>>>(degi, fillc, bnsums, N);
    deg_kernel<<<(E + 255) / 256, 256, 0, stream>>>(dstp, degi, E);
    scan_kernel<<<1, 1024, 0, stream>>>(degi, row_ptr, nrm, N);
    fill_kernel<<<(E + 255) / 256, 256, 0, stream>>>(srcp, dstp, row_ptr, fillc, nrm, edges, E);
    wcvt_kernel<<<dim3(8, 8, NLAYERS), 256, 0, stream>>>(W, wt);
    embed_kernel<<<N, 256, 0, stream>>>(x, emb, hbA, N);

    unsigned short* hbcur = hbA;
    unsigned short* hboth = hbB;
    int aggGrid = ((N + 3) / 4) * 2;
    for (int l = 0; l < NLAYERS; ++l) {
        float* lsums = bnsums + (size_t)l * 2 * HID;
        agg_ep_kernel<<<aggGrid, 256, 0, stream>>>(hbcur, row_ptr, edges, nrm, aggb, N);
        dim3 ggrid((N + 63) / 64, 4);
        mfma_gemm<<<ggrid, 256, 0, stream>>>(aggb, wt + (size_t)l * HID * HID,
                                             b + (size_t)l * HID, hwb, lsums, N);
        bn_kernel<<<((size_t)N * HID / 4 + 255) / 256, 256, 0, stream>>>(
            hwb, lsums, gamma + (size_t)l * HID, beta + (size_t)l * HID,
            hbcur, hboth, N);
        unsigned short* tb = hbcur; hbcur = hboth; hboth = tb;
    }

    pool_mlp_kernel<<<NGRAPHS, 256, 0, stream>>>(hbcur, batch, N, W1, b1, W2, b2, W3, b3, out);
}